// Round 3
// baseline (715.150 us; speedup 1.0000x reference)
//
#include <hip/hip_runtime.h>

typedef unsigned short u16;
typedef unsigned int u32;
typedef __bf16 bf16x8 __attribute__((ext_vector_type(8)));
typedef float f32x4 __attribute__((ext_vector_type(4)));

__device__ __forceinline__ u16 f2bf(float f) {
    union { float f; u32 u; } v; v.f = f;
    u32 r = v.u + 0x7FFFu + ((v.u >> 16) & 1u);   // RNE
    return (u16)(r >> 16);
}

// ---------------------------------------------------------------------------
// bf16 GEMM: C[M,N] = A[M,K] @ Bt[N,K]^T (+bias, optional relu)
// 128x128 tile, BK=64, 4 waves (2x2), 16x16x32 MFMA, global_load_lds width 16,
// XOR-swizzled LDS (chunk ^= row&7) to break the 128B-stride bank conflict.
// M % 128 == 0, N % 128 == 0, K % 64 == 0 required.
// ---------------------------------------------------------------------------
__global__ __launch_bounds__(256) void gemm_bt(
    const u16* __restrict__ A, const u16* __restrict__ Bt,
    float* __restrict__ C, const float* __restrict__ bias,
    int M, int N, int K, int relu)
{
    __shared__ char lA[128 * 64 * 2];
    __shared__ char lB[128 * 64 * 2];
    const int t = threadIdx.x;
    const int w = t >> 6, l = t & 63;
    const int bn = blockIdx.x, bm = blockIdx.y;
    const int wr = w >> 1, wc = w & 1;

    const int srow = w * 8 + (l >> 3);
    const int scol = ((l & 7) ^ (l >> 3)) << 3;     // element offset of swizzled chunk
    const u16* gA = A + (size_t)(bm * 128 + srow) * K + scol;
    const u16* gB = Bt + (size_t)(bn * 128 + srow) * K + scol;

    f32x4 zero = {0.f, 0.f, 0.f, 0.f};
    f32x4 acc[4][4];
#pragma unroll
    for (int i = 0; i < 4; i++)
#pragma unroll
        for (int j = 0; j < 4; j++) acc[i][j] = zero;

    const int arow = wr * 64 + (l & 15);
    const int brow = wc * 64 + (l & 15);
    const int kx = l >> 4;
    const int sw = l & 7;       // == row&7 for fragment rows

    for (int k0 = 0; k0 < K; k0 += 64) {
#pragma unroll
        for (int c2 = 0; c2 < 4; ++c2) {
            __builtin_amdgcn_global_load_lds(
                (const __attribute__((address_space(1))) void*)(gA + (size_t)c2 * 32 * K + k0),
                (__attribute__((address_space(3))) void*)(lA + c2 * 4096 + w * 1024), 16, 0, 0);
            __builtin_amdgcn_global_load_lds(
                (const __attribute__((address_space(1))) void*)(gB + (size_t)c2 * 32 * K + k0),
                (__attribute__((address_space(3))) void*)(lB + c2 * 4096 + w * 1024), 16, 0, 0);
        }
        __syncthreads();
#pragma unroll
        for (int kk = 0; kk < 2; ++kk) {
            bf16x8 af[4], bfr[4];
#pragma unroll
            for (int mi = 0; mi < 4; ++mi)
                af[mi] = *(const bf16x8*)(lA + (arow + mi * 16) * 128 + (((kk * 4 + kx) ^ sw) << 4));
#pragma unroll
            for (int ni = 0; ni < 4; ++ni)
                bfr[ni] = *(const bf16x8*)(lB + (brow + ni * 16) * 128 + (((kk * 4 + kx) ^ sw) << 4));
#pragma unroll
            for (int mi = 0; mi < 4; ++mi)
#pragma unroll
                for (int ni = 0; ni < 4; ++ni)
                    acc[mi][ni] = __builtin_amdgcn_mfma_f32_16x16x32_bf16(af[mi], bfr[ni], acc[mi][ni], 0, 0, 0);
        }
        __syncthreads();
    }

    const int cm = bm * 128 + wr * 64;
    const int cn = bn * 128 + wc * 64;
#pragma unroll
    for (int mi = 0; mi < 4; ++mi) {
#pragma unroll
        for (int ni = 0; ni < 4; ++ni) {
            int row0 = cm + mi * 16 + (l >> 4) * 4;
            int col = cn + ni * 16 + (l & 15);
            float bv = bias ? bias[col] : 0.f;
#pragma unroll
            for (int r = 0; r < 4; ++r) {
                float v = acc[mi][ni][r] + bv;
                if (relu) v = fmaxf(v, 0.f);
                C[(size_t)(row0 + r) * N + col] = v;
            }
        }
    }
}

// ---------------------------------------------------------------------------
__global__ void conv_bf16_vec(const float* __restrict__ in, u16* __restrict__ out, long n4)
{
    long i = (long)blockIdx.x * blockDim.x + threadIdx.x;
    long stride = (long)gridDim.x * blockDim.x;
    for (; i < n4; i += stride) {
        float4 v = ((const float4*)in)[i];
        ushort4 o;
        o.x = f2bf(v.x); o.y = f2bf(v.y); o.z = f2bf(v.z); o.w = f2bf(v.w);
        ((ushort4*)out)[i] = o;
    }
}

// nodes fp32 [Nn,768] -> bf16 [Mpad,768], pad rows zero
__global__ void conv_nodes(const float* __restrict__ nodes, u16* __restrict__ out, int Nn, int Mpad)
{
    long i = (long)blockIdx.x * blockDim.x + threadIdx.x;
    long stride = (long)gridDim.x * blockDim.x;
    long n4 = (long)Mpad * 192;
    for (; i < n4; i += stride) {
        long row = i / 192;
        ushort4 o;
        if ((int)row < Nn) {
            float4 v = ((const float4*)nodes)[i];
            o.x = f2bf(v.x); o.y = f2bf(v.y); o.z = f2bf(v.z); o.w = f2bf(v.w);
        } else { o.x = 0; o.y = 0; o.z = 0; o.w = 0; }
        ((ushort4*)out)[i] = o;
    }
}

// in [Rr,Cc] fp32 -> out [Cc,Rr] bf16
__global__ void transpose_bf16(const float* __restrict__ in, u16* __restrict__ out, int Rr, int Cc)
{
    __shared__ float tile[32][33];
    int c0 = blockIdx.x * 32, r0 = blockIdx.y * 32;
    int tx = threadIdx.x, ty = threadIdx.y;
    for (int dy = 0; dy < 32; dy += 8) {
        int r = r0 + ty + dy, c = c0 + tx;
        tile[ty + dy][tx] = (r < Rr && c < Cc) ? in[(size_t)r * Cc + c] : 0.f;
    }
    __syncthreads();
    for (int dy = 0; dy < 32; dy += 8) {
        int c = c0 + ty + dy, r = r0 + tx;
        if (c < Cc && r < Rr) out[(size_t)c * Rr + r] = f2bf(tile[tx][ty + dy]);
    }
}

__global__ void gather_x0(const float* __restrict__ nodes, const int* __restrict__ opt,
                          float* __restrict__ x0, u16* __restrict__ x0b, int H)
{
    int r = blockIdx.x;
    size_t srcb = (size_t)opt[r] * H;
    for (int c = threadIdx.x; c < H; c += blockDim.x) {
        float v = nodes[srcb + c];
        x0[(size_t)r * H + c] = v;
        x0b[(size_t)r * H + c] = f2bf(v);
    }
}

__global__ void scatter_opts(const float* __restrict__ x2, const int* __restrict__ opt,
                             u16* __restrict__ nodes2b, int H)
{
    int r = blockIdx.x;
    size_t dstb = (size_t)opt[r] * H;
    for (int c = threadIdx.x; c < H; c += blockDim.x)
        nodes2b[dstb + c] = f2bf(x2[(size_t)r * H + c]);
}

// S=4 attention, one block per (batch,head), wave w owns query row w
__global__ __launch_bounds__(256) void attn_small(
    const float* __restrict__ qkv, float* __restrict__ out, int H, int nh, int hd)
{
    int b = blockIdx.x / nh, h = blockIdx.x % nh;
    int w = threadIdx.x >> 6, l = threadIdx.x & 63;
    __shared__ float sc[4][4];
    int qs = 3 * H;
    const float* qr = qkv + (size_t)(b * 4 + w) * qs + h * hd;
    float scale = rsqrtf((float)hd);
    for (int sj = 0; sj < 4; ++sj) {
        const float* kr = qkv + (size_t)(b * 4 + sj) * qs + H + h * hd;
        float p = 0.f;
        for (int i = l; i < hd; i += 64) p += qr[i] * kr[i];
        for (int off = 32; off; off >>= 1) p += __shfl_down(p, off, 64);
        if (l == 0) sc[w][sj] = p * scale;
    }
    __syncthreads();
    float a0 = sc[w][0], a1 = sc[w][1], a2 = sc[w][2], a3 = sc[w][3];
    float mx = fmaxf(fmaxf(a0, a1), fmaxf(a2, a3));
    float e0 = __expf(a0 - mx), e1 = __expf(a1 - mx), e2 = __expf(a2 - mx), e3 = __expf(a3 - mx);
    float inv = 1.f / (e0 + e1 + e2 + e3);
    e0 *= inv; e1 *= inv; e2 *= inv; e3 *= inv;
    const float* v0 = qkv + (size_t)(b * 4 + 0) * qs + 2 * H + h * hd;
    const float* v1 = v0 + qs; const float* v2 = v1 + qs; const float* v3 = v2 + qs;
    float* orow = out + (size_t)(b * 4 + w) * H + h * hd;
    for (int i = l; i < hd; i += 64)
        orow[i] = e0 * v0[i] + e1 * v1[i] + e2 * v2[i] + e3 * v3[i];
}

// LN over 768: out = g*(x+res - m)*rinv + b, optional bf16 copy
__global__ __launch_bounds__(256) void ln768(
    const float* __restrict__ x, const float* __restrict__ res,
    const float* __restrict__ g, const float* __restrict__ be,
    float* __restrict__ out, u16* __restrict__ outb)
{
    int row = blockIdx.x, t = threadIdx.x;
    const float* xr = x + (size_t)row * 768;
    const float* rr = res + (size_t)row * 768;
    float v[3]; float s = 0.f, q = 0.f;
#pragma unroll
    for (int i = 0; i < 3; i++) {
        float a = xr[t + i * 256] + rr[t + i * 256];
        v[i] = a; s += a; q += a * a;
    }
    for (int off = 32; off; off >>= 1) { s += __shfl_down(s, off, 64); q += __shfl_down(q, off, 64); }
    __shared__ float ss[4], qq[4];
    int w = t >> 6, l = t & 63;
    if (l == 0) { ss[w] = s; qq[w] = q; }
    __syncthreads();
    s = ss[0] + ss[1] + ss[2] + ss[3];
    q = qq[0] + qq[1] + qq[2] + qq[3];
    float m = s * (1.f / 768.f);
    float ri = rsqrtf(q * (1.f / 768.f) - m * m + 1e-5f);
#pragma unroll
    for (int i = 0; i < 3; i++) {
        int c = t + i * 256;
        float o = g[c] * (v[i] - m) * ri + be[c];
        out[(size_t)row * 768 + c] = o;
        if (outb) outb[(size_t)row * 768 + c] = f2bf(o);
    }
}

__global__ void ln64(const float* __restrict__ x, const float* __restrict__ res,
                     const float* __restrict__ g, const float* __restrict__ be,
                     float* __restrict__ out)
{
    int row = blockIdx.x, l = threadIdx.x;
    float a = x[(size_t)row * 64 + l] + res[(size_t)row * 64 + l];
    float s = a, q = a * a;
    for (int off = 32; off; off >>= 1) { s += __shfl_down(s, off, 64); q += __shfl_down(q, off, 64); }
    s = __shfl(s, 0, 64); q = __shfl(q, 0, 64);
    float m = s * (1.f / 64.f);
    float ri = rsqrtf(q * (1.f / 64.f) - m * m + 1e-5f);
    out[(size_t)row * 64 + l] = g[l] * (a - m) * ri + be[l];
}

// generic small linear: Y[row,j] = act(X[row,:] . Wt[j,:] + bias[j])
__global__ void lin_small(const float* __restrict__ X, const float* __restrict__ Wt,
                          const float* __restrict__ bias, float* __restrict__ Y,
                          int N, int K, int act)
{
    extern __shared__ float xr[];
    int row = blockIdx.x;
    const float* xp = X + (size_t)row * K;
    for (int i = threadIdx.x; i < K; i += blockDim.x) xr[i] = xp[i];
    __syncthreads();
    const float4* xr4 = (const float4*)xr;
    for (int j = threadIdx.x; j < N; j += blockDim.x) {
        const float4* wp4 = (const float4*)(Wt + (size_t)j * K);
        float acc = 0.f;
        for (int k = 0; k < (K >> 2); k++) {
            float4 wv = wp4[k], xv = xr4[k];
            acc += wv.x * xv.x + wv.y * xv.y + wv.z * xv.z + wv.w * xv.w;
        }
        float a = acc + (bias ? bias[j] : 0.f);
        if (act == 1) a = fmaxf(a, 0.f);
        else if (act == 2) a = tanhf(a);
        Y[(size_t)row * N + j] = a;
    }
}

__global__ void edge_count(const int* __restrict__ ei, int* __restrict__ cnt, int E)
{
    int e = blockIdx.x * blockDim.x + threadIdx.x;
    if (e < E) atomicAdd(&cnt[ei[E + e]], 1);
}

// out1[dst] += P[src] / max(cnt[dst],1)   (768 wide, one wave per edge)
__global__ void edge_agg(const int* __restrict__ ei, const int* __restrict__ cnt,
                         const float* __restrict__ P, float* __restrict__ out1, int E)
{
    int w = threadIdx.x >> 6, l = threadIdx.x & 63;
    int e = blockIdx.x * 4 + w;
    if (e >= E) return;
    int s = ei[e], d = ei[E + e];
    float sc = 1.f / (float)max(cnt[d], 1);
    const float* ps = P + (size_t)s * 768;
    float* od = out1 + (size_t)d * 768;
#pragma unroll
    for (int i = 0; i < 12; i++) {
        int j = l + i * 64;
        atomicAdd(&od[j], ps[j] * sc);
    }
}

// out2[dst, 0:64] += C2[src, 0:64]  (GraphConv add-aggregation, projected first)
__global__ void edge_gc(const int* __restrict__ ei, const float* __restrict__ C2,
                        float* __restrict__ out2, int E)
{
    int w = threadIdx.x >> 6, l = threadIdx.x & 63;
    int e = blockIdx.x * 4 + w;
    if (e >= E) return;
    int s = ei[e], d = ei[E + e];
    atomicAdd(&out2[(size_t)d * 64 + l], C2[(size_t)s * 128 + l]);
}

__global__ void out2_init(const float* __restrict__ C2, const float* __restrict__ bg,
                          float* __restrict__ out2, int Nn)
{
    size_t i = (size_t)blockIdx.x * blockDim.x + threadIdx.x;
    size_t tot = (size_t)Nn * 64;
    if (i < tot) {
        size_t n = i >> 6; int j = (int)(i & 63);
        out2[i] = C2[n * 128 + 64 + j] + bg[j];
    }
}

__global__ void gather_x20(const float* __restrict__ out2, const int* __restrict__ opt,
                           float* __restrict__ x20)
{
    int r = blockIdx.x, c = threadIdx.x;
    x20[(size_t)r * 64 + c] = out2[(size_t)opt[r] * 64 + c];
}

// ---------------------------------------------------------------------------
extern "C" void kernel_launch(void* const* d_in, const int* in_sizes, int n_in,
                              void* d_out, int out_size, void* d_ws, size_t ws_size,
                              hipStream_t stream)
{
    const float* nodes  = (const float*)d_in[0];
    const int*   ei     = (const int*)d_in[1];
    const int*   opt    = (const int*)d_in[2];
    const float* w_qkv1 = (const float*)d_in[3];
    const float* b_qkv1 = (const float*)d_in[4];
    const float* w_o1   = (const float*)d_in[5];
    const float* b_o1   = (const float*)d_in[6];
    const float* g1a    = (const float*)d_in[7];
    const float* bb1a   = (const float*)d_in[8];
    const float* w_ff1a = (const float*)d_in[9];
    const float* bf1a   = (const float*)d_in[10];
    const float* w_ff1b = (const float*)d_in[11];
    const float* bf1b   = (const float*)d_in[12];
    const float* g1b    = (const float*)d_in[13];
    const float* bb1b   = (const float*)d_in[14];
    // d_in[15..28]: wq..b6 — dead code (edge_type ≡ 0, see analysis)
    const float* w_rel  = (const float*)d_in[29];
    const float* w_root = (const float*)d_in[30];
    const float* b_rgcn = (const float*)d_in[31];
    const float* wg_rel = (const float*)d_in[32];
    const float* wg_root= (const float*)d_in[33];
    const float* bg     = (const float*)d_in[34];
    const float* w_qkv2 = (const float*)d_in[35];
    const float* b_qkv2 = (const float*)d_in[36];
    const float* w_o2   = (const float*)d_in[37];
    const float* b_o2   = (const float*)d_in[38];
    const float* g2a    = (const float*)d_in[39];
    const float* bb2a   = (const float*)d_in[40];
    const float* w_ff2a = (const float*)d_in[41];
    const float* bf2a   = (const float*)d_in[42];
    const float* w_ff2b = (const float*)d_in[43];
    const float* bf2b   = (const float*)d_in[44];
    const float* g2b    = (const float*)d_in[45];
    const float* bb2b   = (const float*)d_in[46];
    const float* w_l1   = (const float*)d_in[47];
    const float* b_l1   = (const float*)d_in[48];
    const float* w_l2   = (const float*)d_in[49];
    const float* b_l2   = (const float*)d_in[50];

    const int H = 768, F = 2048;
    const int Nn = in_sizes[0] / H;            // 20000
    const int E  = in_sizes[1] / 2;            // 40000
    const int R  = in_sizes[2];                // 256 option rows
    const int Mpad = (Nn + 127) & ~127;        // 20096
    const int Bb = R / 4;                      // 64 batches

    char* ws = (char*)d_ws;
    size_t off = 0;
    auto alloc = [&](size_t b) -> char* {
        char* p = ws + off; off += (b + 255) & ~(size_t)255; return p;
    };
    // bf16 weights
    u16* wqkv1b  = (u16*)alloc((size_t)3 * H * H * 2);
    u16* wo1b    = (u16*)alloc((size_t)H * H * 2);
    u16* wff1ab  = (u16*)alloc((size_t)F * H * 2);
    u16* wff1bb  = (u16*)alloc((size_t)H * F * 2);
    u16* wrel0tb = (u16*)alloc((size_t)H * H * 2);
    u16* wroottb = (u16*)alloc((size_t)H * H * 2);
    u16* W2tb    = (u16*)alloc((size_t)128 * H * 2);
    // encoder1 activations
    float* x0   = (float*)alloc((size_t)R * H * 4);
    u16*  x0b   = (u16*)alloc((size_t)R * H * 2);
    float* qkvb = (float*)alloc((size_t)R * 3 * H * 4);
    float* atno = (float*)alloc((size_t)R * H * 4);
    u16*  atnob = (u16*)alloc((size_t)R * H * 2);
    float* obuf = (float*)alloc((size_t)R * H * 4);
    float* x1   = (float*)alloc((size_t)R * H * 4);
    u16*  x1b   = (u16*)alloc((size_t)R * H * 2);
    float* ffh  = (float*)alloc((size_t)R * F * 4);
    u16*  ffhb  = (u16*)alloc((size_t)R * F * 2);
    float* ffo  = (float*)alloc((size_t)R * H * 4);
    float* x2   = (float*)alloc((size_t)R * H * 4);
    // big buffers
    u16*  nodes2b = (u16*)alloc((size_t)Mpad * H * 2);
    float* P      = (float*)alloc((size_t)Mpad * H * 4);
    float* out1   = (float*)alloc((size_t)Mpad * H * 4);
    int*  cnt     = (int*)alloc((size_t)Nn * 4);
    float* out2   = (float*)alloc((size_t)Nn * 64 * 4);
    // aliases: nodes2b dead after the two big GEMMs; P dead after edge_agg
    u16*  out1b = nodes2b;
    float* C2   = P;
    // encoder2 activations
    float* x20   = (float*)alloc((size_t)R * 64 * 4);
    float* qkv2b = (float*)alloc((size_t)R * 192 * 4);
    float* a2o   = (float*)alloc((size_t)R * 64 * 4);
    float* o2b   = (float*)alloc((size_t)R * 64 * 4);
    float* x21   = (float*)alloc((size_t)R * 64 * 4);
    float* ffh2  = (float*)alloc((size_t)R * F * 4);
    float* ffo2  = (float*)alloc((size_t)R * 64 * 4);
    float* x22   = (float*)alloc((size_t)R * 64 * 4);
    float* l1b   = (float*)alloc((size_t)R * 64 * 4);
    (void)ws_size; (void)n_in; (void)out_size;

    // ---- weight conversions (every call; ws is re-poisoned) ----
    conv_bf16_vec<<<512, 256, 0, stream>>>(w_qkv1, wqkv1b, (long)3 * H * H / 4);
    conv_bf16_vec<<<512, 256, 0, stream>>>(w_o1, wo1b, (long)H * H / 4);
    conv_bf16_vec<<<512, 256, 0, stream>>>(w_ff1a, wff1ab, (long)F * H / 4);
    conv_bf16_vec<<<512, 256, 0, stream>>>(w_ff1b, wff1bb, (long)H * F / 4);
    transpose_bf16<<<dim3(24, 24), dim3(32, 8), 0, stream>>>(w_rel, wrel0tb, H, H);     // w_rel[0]^T
    transpose_bf16<<<dim3(24, 24), dim3(32, 8), 0, stream>>>(w_root, wroottb, H, H);
    transpose_bf16<<<dim3(2, 24), dim3(32, 8), 0, stream>>>(wg_rel, W2tb, H, 64);       // rows 0:64
    transpose_bf16<<<dim3(2, 24), dim3(32, 8), 0, stream>>>(wg_root, W2tb + (size_t)64 * H, H, 64);

    // ---- encoder layer 1 on option nodes (256 x 768) ----
    gather_x0<<<R, 256, 0, stream>>>(nodes, opt, x0, x0b, H);
    gemm_bt<<<dim3(3 * H / 128, R / 128), 256, 0, stream>>>(x0b, wqkv1b, qkvb, b_qkv1, R, 3 * H, H, 0);
    attn_small<<<Bb * 2, 256, 0, stream>>>(qkvb, atno, H, 2, H / 2);
    conv_bf16_vec<<<256, 256, 0, stream>>>(atno, atnob, (long)R * H / 4);
    gemm_bt<<<dim3(H / 128, R / 128), 256, 0, stream>>>(atnob, wo1b, obuf, b_o1, R, H, H, 0);
    ln768<<<R, 256, 0, stream>>>(obuf, x0, g1a, bb1a, x1, x1b);
    gemm_bt<<<dim3(F / 128, R / 128), 256, 0, stream>>>(x1b, wff1ab, ffh, bf1a, R, F, H, 1);
    conv_bf16_vec<<<256, 256, 0, stream>>>(ffh, ffhb, (long)R * F / 4);
    gemm_bt<<<dim3(H / 128, R / 128), 256, 0, stream>>>(ffhb, wff1bb, ffo, bf1b, R, H, F, 0);
    ln768<<<R, 256, 0, stream>>>(ffo, x1, g1b, bb1b, x2, nullptr);

    // ---- nodes2 (bf16, padded) ----
    conv_nodes<<<2048, 256, 0, stream>>>(nodes, nodes2b, Nn, Mpad);
    scatter_opts<<<R, 256, 0, stream>>>(x2, opt, nodes2b, H);

    // ---- RGCN (only rel 0 is live): P = nodes2@w_rel0 ; out1 = nodes2@w_root + b + mean-agg(P) ----
    gemm_bt<<<dim3(H / 128, Mpad / 128), 256, 0, stream>>>(nodes2b, wrel0tb, P, nullptr, Mpad, H, H, 0);
    gemm_bt<<<dim3(H / 128, Mpad / 128), 256, 0, stream>>>(nodes2b, wroottb, out1, b_rgcn, Mpad, H, H, 0);
    hipMemsetAsync(cnt, 0, (size_t)Nn * 4, stream);
    edge_count<<<(E + 255) / 256, 256, 0, stream>>>(ei, cnt, E);
    edge_agg<<<(E + 3) / 4, 256, 0, stream>>>(ei, cnt, P, out1, E);

    // ---- GraphConv: project first (segment_sum commutes with matmul), then scatter ----
    conv_bf16_vec<<<2048, 256, 0, stream>>>(out1, out1b, (long)Mpad * H / 4);
    gemm_bt<<<dim3(1, Mpad / 128), 256, 0, stream>>>(out1b, W2tb, C2, nullptr, Mpad, 128, H, 0);
    out2_init<<<(Nn * 64 + 255) / 256, 256, 0, stream>>>(C2, bg, out2, Nn);
    edge_gc<<<(E + 3) / 4, 256, 0, stream>>>(ei, C2, out2, E);

    // ---- encoder layer 2 (256 x 64) + readout ----
    gather_x20<<<R, 64, 0, stream>>>(out2, opt, x20);
    lin_small<<<R, 192, 64 * 4, stream>>>(x20, w_qkv2, b_qkv2, qkv2b, 192, 64, 0);
    attn_small<<<Bb * 2, 256, 0, stream>>>(qkv2b, a2o, 64, 2, 32);
    lin_small<<<R, 64, 64 * 4, stream>>>(a2o, w_o2, b_o2, o2b, 64, 64, 0);
    ln64<<<R, 64, 0, stream>>>(o2b, x20, g2a, bb2a, x21);
    lin_small<<<R, 256, 64 * 4, stream>>>(x21, w_ff2a, bf2a, ffh2, F, 64, 1);
    lin_small<<<R, 64, F * 4, stream>>>(ffh2, w_ff2b, bf2b, ffo2, 64, F, 0);
    ln64<<<R, 64, 0, stream>>>(ffo2, x21, g2b, bb2b, x22);
    lin_small<<<R, 64, 64 * 4, stream>>>(x22, w_l1, b_l1, l1b, 64, 64, 2);
    lin_small<<<R, 64, 64 * 4, stream>>>(l1b, w_l2, b_l2, (float*)d_out, 1, 64, 0);
}